// Round 8
// baseline (681.383 us; speedup 1.0000x reference)
//
#include <hip/hip_runtime.h>

// LiquidTimeConstantCell fused kernel, MI355X gfx950 — R14.
// R13 structure (barrier-free wave-private RK4, no spill, 248 VGPR) with the
// residency fixed. R13 post-mortem: occupancy 11% => only ONE 4-wave block per
// CU resident (2x68.6KB should fit in 160KB but measurably doesn't) => 512
// blocks ran as 2 sequential rounds at 1 wave/SIMD, fully exposing the serial
// feval->pointwise->zwrite chain (all pipes <31%).
// R14: ONE 8-wave block per CU. ROWS=128, 512 thr (8 waves x 16 rows),
// grid=256 = exactly 1 block/CU, single round, no tail. LDS ~100.5KB fits as
// a single workgroup -> residency is unambiguous: 8 waves/CU, 2 waves/SIMD.
// Per-wave code identical to R13. __launch_bounds__(512,1) keeps the 256-VGPR
// cap (empirical law cap=256/arg2, 6 data points R8-R13).

constexpr int kB   = 32768;
constexpr int kH   = 128;
constexpr int kIn  = 128;
constexpr int kT   = 10;
constexpr int ROWS = 128;    // rows per block (8 waves x 16)
constexpr int RW   = 16;     // rows per wave
constexpr int LDSW = 136;    // padded bf16 row stride (keeps b128 rows 16B-aligned)
constexpr int HIN  = 256;    // H + IN
constexpr int NHT  = 8;      // h tiles of 16

typedef __bf16 bf16;
typedef __attribute__((ext_vector_type(8))) __bf16 bf16x8;
typedef __attribute__((ext_vector_type(4))) __bf16 bf16x4;
typedef __attribute__((ext_vector_type(4))) float  f32x4;

__device__ __forceinline__ float sigmoid_(float v) {
  return __fdividef(1.0f, 1.0f + __expf(-v));
}

__device__ __forceinline__ bf16x8 cvt8(const float* p) {
  float4 f0 = *(const float4*)p;
  float4 f1 = *(const float4*)(p + 4);
  bf16x8 t;
  t[0]=(bf16)f0.x; t[1]=(bf16)f0.y; t[2]=(bf16)f0.z; t[3]=(bf16)f0.w;
  t[4]=(bf16)f1.x; t[5]=(bf16)f1.y; t[6]=(bf16)f1.z; t[7]=(bf16)f1.w;
  return t;
}

__global__ __launch_bounds__(512, 1) void ltc_kernel(
    const float* __restrict__ x,     const float* __restrict__ hidden,
    const float* __restrict__ ts,    const float* __restrict__ wiring,
    const float* __restrict__ W,     const float* __restrict__ bb_,
    const float* __restrict__ W_in,  const float* __restrict__ b_in,
    const float* __restrict__ W_upd, const float* __restrict__ b_upd,
    const float* __restrict__ W_rst, const float* __restrict__ b_rst,
    float* __restrict__ out)   // FP32 output: [new_hidden (B,H); ode_out (T,B,H)]
{
  __shared__ bf16 poolX [ROWS][LDSW];  // x tile (gates); z-tiles overlay (loop)
  __shared__ bf16 poolHd[ROWS][LDSW];  // hidden tile (gates)
  __shared__ bf16 weffF[32][64][8];    // W_eff in A-frag order: [ht*4+kk][lane][8]
  __shared__ float sbias[kH];
  __shared__ float stsv[kT];

  const int tid  = threadIdx.x;
  const int wv   = tid >> 6;           // 0..7
  const int lane = tid & 63;
  const int qd   = lane >> 4;          // quad 0..3
  const int l16  = lane & 15;
  const int r0   = blockIdx.x * ROWS;
  const int rbase = wv * RW;
  const int grow  = r0 + rbase + l16;  // lane's global batch row (one row!)

  if (tid < kT) stsv[tid] = ts[tid];
  if (tid < kH) sbias[tid] = bb_[tid];

  // ---- stage x & hidden tiles into LDS as bf16 (128x32 float4, 512 thr) ----
#pragma unroll
  for (int i = 0; i < 8; ++i) {
    int idx = i*512 + tid;
    int row = idx >> 5;
    int c4  = (idx & 31) * 4;
    float4 vx = *(const float4*)(x      + (size_t)(r0+row)*kIn + c4);
    float4 vh = *(const float4*)(hidden + (size_t)(r0+row)*kH  + c4);
    bf16x4 bx; bx[0]=(bf16)vx.x; bx[1]=(bf16)vx.y; bx[2]=(bf16)vx.z; bx[3]=(bf16)vx.w;
    bf16x4 bh; bh[0]=(bf16)vh.x; bh[1]=(bf16)vh.y; bh[2]=(bf16)vh.z; bh[3]=(bf16)vh.w;
    *(bf16x4*)&poolX [row][c4] = bx;
    *(bf16x4*)&poolHd[row][c4] = bh;
  }

  // ---- stage W_eff = W .* wiring into LDS in A-frag order (4 frags/wave) ----
#pragma unroll
  for (int j = 0; j < 4; ++j) {
    int f = wv*4 + j, ht = f >> 2, kk = f & 3;
    const float* wp = W      + (size_t)(ht*16 + l16)*kH + kk*32 + qd*8;
    const float* mp = wiring + (size_t)(ht*16 + l16)*kH + kk*32 + qd*8;
    float4 w0 = *(const float4*)wp, w1 = *(const float4*)(wp+4);
    float4 m0 = *(const float4*)mp, m1 = *(const float4*)(mp+4);
    bf16x8 t;
    t[0]=(bf16)(w0.x*m0.x); t[1]=(bf16)(w0.y*m0.y);
    t[2]=(bf16)(w0.z*m0.z); t[3]=(bf16)(w0.w*m0.w);
    t[4]=(bf16)(w1.x*m1.x); t[5]=(bf16)(w1.y*m1.y);
    t[6]=(bf16)(w1.z*m1.z); t[7]=(bf16)(w1.w*m1.w);
    *(bf16x8*)&weffF[f][lane][0] = t;
  }
  __syncthreads();   // BARRIER 1: x/hidden/weffF/sbias/stsv visible

  // ---- gates, wave-private, lane owns row=grow, h=16ht+4qd+i ----
  // B-frags: combined[row][k], k<128 hidden, k>=128 x.
  bf16x8 cb[8];
#pragma unroll
  for (int kk = 0; kk < 4; ++kk)
    cb[kk]   = *(const bf16x8*)&poolHd[rbase + l16][kk*32 + qd*8];
#pragma unroll
  for (int kk = 0; kk < 4; ++kk)
    cb[4+kk] = *(const bf16x8*)&poolX [rbase + l16][kk*32 + qd*8];

  f32x4 XP[NHT], Ug[NHT], Rg[NHT];
#pragma unroll
  for (int ht = 0; ht < NHT; ++ht) {
    float4 bi = *(const float4*)(b_in  + 16*ht + 4*qd);
    float4 bu = *(const float4*)(b_upd + 16*ht + 4*qd);
    float4 br = *(const float4*)(b_rst + 16*ht + 4*qd);
    XP[ht] = f32x4{bi.x, bi.y, bi.z, bi.w};
    Ug[ht] = f32x4{bu.x, bu.y, bu.z, bu.w};
    Rg[ht] = f32x4{br.x, br.y, br.z, br.w};
  }
#pragma unroll
  for (int ht = 0; ht < NHT; ++ht) {
    const float* wu = W_upd + (size_t)(16*ht + l16)*HIN + qd*8;
    const float* wr = W_rst + (size_t)(16*ht + l16)*HIN + qd*8;
#pragma unroll
    for (int kk = 0; kk < 8; ++kk) {
      Ug[ht] = __builtin_amdgcn_mfma_f32_16x16x32_bf16(cvt8(wu + kk*32), cb[kk], Ug[ht], 0,0,0);
      Rg[ht] = __builtin_amdgcn_mfma_f32_16x16x32_bf16(cvt8(wr + kk*32), cb[kk], Rg[ht], 0,0,0);
    }
    const float* wi = W_in + (size_t)(16*ht + l16)*kIn + qd*8;
#pragma unroll
    for (int kk = 0; kk < 4; ++kk)
      XP[ht] = __builtin_amdgcn_mfma_f32_16x16x32_bf16(cvt8(wi + kk*32), cb[4+kk], XP[ht], 0,0,0);
  }

  f32x4 h[NHT], z[NHT], hacc[NHT], xp1[NHT], K[NHT];
  bf16x4 ub[NHT], h0b[NHT];
#pragma unroll
  for (int ht = 0; ht < NHT; ++ht) {
    float4 hv = *(const float4*)(hidden + (size_t)grow*kH + 16*ht + 4*qd);
    h[ht][0] = sigmoid_(Rg[ht][0]) * hv.x;
    h[ht][1] = sigmoid_(Rg[ht][1]) * hv.y;
    h[ht][2] = sigmoid_(Rg[ht][2]) * hv.z;
    h[ht][3] = sigmoid_(Rg[ht][3]) * hv.w;
#pragma unroll
    for (int i = 0; i < 4; ++i) {
      ub[ht][i]  = (bf16)sigmoid_(Ug[ht][i]);   // u parked in VGPR bf16
      h0b[ht][i] = (bf16)h[ht][i];              // h0 parked in VGPR bf16
      xp1[ht][i] = XP[ht][i] + 1.0f;            // x_proj + 1 (folds tanh const)
      z[ht][i]   = h[ht][i];
    }
  }
  __syncthreads();   // BARRIER 2: gates done reading poolX/poolHd -> overlay

  // ---- wave-private z tile overlays poolX rows [rbase, rbase+16) ----
  bf16 (*zt)[LDSW] = (bf16 (*)[LDSW])&poolX[rbase][0];
  float* odeB = out + (size_t)kB*kH;

#pragma unroll
  for (int ht = 0; ht < NHT; ++ht) {
    bf16x4 p;
    p[0]=(bf16)h[ht][0]; p[1]=(bf16)h[ht][1]; p[2]=(bf16)h[ht][2]; p[3]=(bf16)h[ht][3];
    *(bf16x4*)&zt[l16][16*ht + 4*qd] = p;                       // z = h0
    *(f32x4*)(odeB + (size_t)grow*kH + 16*ht + 4*qd) = h[ht];   // ode_out[0]
  }
  bf16x8 zf[4];
#pragma unroll
  for (int kk = 0; kk < 4; ++kk)
    zf[kk] = *(const bf16x8*)&zt[l16][kk*32 + qd*8];

  // ---- barrier-free RK4 loop: 9 steps x 4 stages, all wave-private ----
  auto feval = [&]() {
#pragma unroll
    for (int ht = 0; ht < NHT; ++ht)
      K[ht] = *(const f32x4*)&sbias[16*ht + 4*qd];   // broadcast LDS read
#pragma unroll
    for (int kk = 0; kk < 4; ++kk)
#pragma unroll
      for (int ht = 0; ht < NHT; ++ht) {
        bf16x8 wf = *(const bf16x8*)&weffF[ht*4 + kk][lane][0];
        K[ht] = __builtin_amdgcn_mfma_f32_16x16x32_bf16(wf, zf[kk], K[ht], 0,0,0);
      }
  };
  auto zwrite = [&]() {   // C-layout write + B-frag readback (in-wave, no barrier)
#pragma unroll
    for (int ht = 0; ht < NHT; ++ht) {
      bf16x4 p;
      p[0]=(bf16)z[ht][0]; p[1]=(bf16)z[ht][1]; p[2]=(bf16)z[ht][2]; p[3]=(bf16)z[ht][3];
      *(bf16x4*)&zt[l16][16*ht + 4*qd] = p;
    }
#pragma unroll
    for (int kk = 0; kk < 4; ++kk)
      zf[kk] = *(const bf16x8*)&zt[l16][kk*32 + qd*8];
  };
  auto kvf = [&](int ht, int i) -> float {
    float m = 2.8853900817779268f * K[ht][i];        // 2*log2(e) * K
    float e = __builtin_amdgcn_exp2f(m);
    float r = __builtin_amdgcn_rcpf(1.0f + e);
    return __builtin_fmaf(-2.0f, r, xp1[ht][i] - z[ht][i]);  // tanh(K)+xp-z
  };

  for (int t = 1; t < kT; ++t) {
    float dt = stsv[t] - stsv[t-1];
    float c6 = dt * (1.0f/6.0f);
    float c3 = dt * (1.0f/3.0f);
    float ch = 0.5f * dt;

    // stage 1
    feval();
#pragma unroll
    for (int ht = 0; ht < NHT; ++ht)
#pragma unroll
      for (int i = 0; i < 4; ++i) {
        float kv = kvf(ht, i);
        hacc[ht][i] = __builtin_fmaf(c6, kv, h[ht][i]);
        z[ht][i]    = __builtin_fmaf(ch, kv, h[ht][i]);
      }
    zwrite();

    // stage 2
    feval();
#pragma unroll
    for (int ht = 0; ht < NHT; ++ht)
#pragma unroll
      for (int i = 0; i < 4; ++i) {
        float kv = kvf(ht, i);
        hacc[ht][i] = __builtin_fmaf(c3, kv, hacc[ht][i]);
        z[ht][i]    = __builtin_fmaf(ch, kv, h[ht][i]);
      }
    zwrite();

    // stage 3
    feval();
#pragma unroll
    for (int ht = 0; ht < NHT; ++ht)
#pragma unroll
      for (int i = 0; i < 4; ++i) {
        float kv = kvf(ht, i);
        hacc[ht][i] = __builtin_fmaf(c3, kv, hacc[ht][i]);
        z[ht][i]    = __builtin_fmaf(dt, kv, h[ht][i]);
      }
    zwrite();

    // stage 4
    feval();
#pragma unroll
    for (int ht = 0; ht < NHT; ++ht)
#pragma unroll
      for (int i = 0; i < 4; ++i) {
        float kv = kvf(ht, i);
        h[ht][i] = __builtin_fmaf(c6, kv, hacc[ht][i]);
        z[ht][i] = h[ht][i];
      }
    zwrite();

    float* odet = odeB + (size_t)t*kB*kH + (size_t)grow*kH;
#pragma unroll
    for (int ht = 0; ht < NHT; ++ht)
      *(f32x4*)(odet + 16*ht + 4*qd) = h[ht];   // ode_out[t] (fp32)
  }

  // ---- final blend: new_hidden = u*h_last + (1-u)*h0 ----
#pragma unroll
  for (int ht = 0; ht < NHT; ++ht) {
    float4 p;
    float uu;
    uu=(float)ub[ht][0]; p.x = uu*h[ht][0] + (1.0f-uu)*(float)h0b[ht][0];
    uu=(float)ub[ht][1]; p.y = uu*h[ht][1] + (1.0f-uu)*(float)h0b[ht][1];
    uu=(float)ub[ht][2]; p.z = uu*h[ht][2] + (1.0f-uu)*(float)h0b[ht][2];
    uu=(float)ub[ht][3]; p.w = uu*h[ht][3] + (1.0f-uu)*(float)h0b[ht][3];
    *(float4*)(out + (size_t)grow*kH + 16*ht + 4*qd) = p;
  }
}

extern "C" void kernel_launch(void* const* d_in, const int* in_sizes, int n_in,
                              void* d_out, int out_size, void* d_ws, size_t ws_size,
                              hipStream_t stream) {
  (void)d_ws; (void)ws_size; (void)out_size;
  // Resolve input order from in_sizes (insurance; documented order expected).
  int ix=0, ih=1, its=2, iwr=3, iW=4, ib=5, iWin=6, ibin=7, iWu=8, ibu=9, iWr=10, ibr=11;
  if (n_in == 12 && in_sizes[2] != 10 && in_sizes[5] == 10) {
    // case-insensitive name-sorted: b,b_in,b_rst,b_upd,hidden,time_span,W,W_in,W_rst,W_upd,wiring,x
    ib=0; ibin=1; ibr=2; ibu=3; ih=4; its=5; iW=6; iWin=7; iWr=8; iWu=9; iwr=10; ix=11;
  }
  const float* x      = (const float*)d_in[ix];
  const float* hidden = (const float*)d_in[ih];
  const float* ts     = (const float*)d_in[its];
  const float* wiring = (const float*)d_in[iwr];
  const float* W      = (const float*)d_in[iW];
  const float* b      = (const float*)d_in[ib];
  const float* W_in   = (const float*)d_in[iWin];
  const float* b_in   = (const float*)d_in[ibin];
  const float* W_upd  = (const float*)d_in[iWu];
  const float* b_upd  = (const float*)d_in[ibu];
  const float* W_rst  = (const float*)d_in[iWr];
  const float* b_rst  = (const float*)d_in[ibr];

  dim3 grid(kB / ROWS);   // 256 blocks = exactly 1 per CU, single round
  dim3 block(512);
  ltc_kernel<<<grid, block, 0, stream>>>(x, hidden, ts, wiring, W, b,
                                         W_in, b_in, W_upd, b_upd, W_rst, b_rst,
                                         (float*)d_out);
}

// Round 9
// 332.405 us; speedup vs baseline: 2.0499x; 2.0499x over previous
//
#include <hip/hip_runtime.h>

// LiquidTimeConstantCell fused kernel, MI355X gfx950 — R15.
// Half-width wave-private pairs: the synthesis of R13 (wave-private serial
// chain, no block-wide phase lock) and multi-wave residency.
// Launch-bounds law (7 pts R8-R14): grantedVGPR = 256/max(blockWaves/4, arg2).
// R13's 248-VGPR wave => 1 wave/SIMD, latency-bound at 188us. R15 halves the
// per-wave h range (NHT=4, 16 rows x 64 h) -> ~108 loop regs -> fits the 128
// cap of __launch_bounds__(256,2), so 2-4 waves/SIMD can reside.
//   - wave pair (same 16 rows, complementary h-halves) exchanges z via a
//     4.25KB ping-pong LDS tile; ONE barrier per RK4 stage (ping-pong makes
//     WAR safe); buffers statically scheduled (4 stages/step = parity even).
//   - block 256 = 2 independent pairs; grid 1024 (32 rows/block).
//   - no gate LDS staging: gate B-frags read direct from global (one-time);
//     LDS = weff 32KB + ztiles 17KB + bias ~= 50KB.
//   - u kept in 8 VGPRs; h0 re-read from ode_out[0] (we wrote it) at epilogue.

constexpr int kB   = 32768;
constexpr int kH   = 128;
constexpr int kIn  = 128;
constexpr int kT   = 10;
constexpr int ROWS = 32;     // rows per block (2 pairs x 16) -> 1024 blocks
constexpr int LDSW = 136;    // padded bf16 row stride
constexpr int HIN  = 256;    // H + IN
constexpr int NHT  = 4;      // h tiles of 16 per wave (64 h = half)

typedef __bf16 bf16;
typedef __attribute__((ext_vector_type(8))) __bf16 bf16x8;
typedef __attribute__((ext_vector_type(4))) __bf16 bf16x4;
typedef __attribute__((ext_vector_type(4))) float  f32x4;

__device__ __forceinline__ float sigmoid_(float v) {
  return __fdividef(1.0f, 1.0f + __expf(-v));
}

__device__ __forceinline__ bf16x8 cvt8(const float* p) {
  float4 f0 = *(const float4*)p;
  float4 f1 = *(const float4*)(p + 4);
  bf16x8 t;
  t[0]=(bf16)f0.x; t[1]=(bf16)f0.y; t[2]=(bf16)f0.z; t[3]=(bf16)f0.w;
  t[4]=(bf16)f1.x; t[5]=(bf16)f1.y; t[6]=(bf16)f1.z; t[7]=(bf16)f1.w;
  return t;
}

__global__ __launch_bounds__(256, 2) void ltc_kernel(
    const float* __restrict__ x,     const float* __restrict__ hidden,
    const float* __restrict__ ts,    const float* __restrict__ wiring,
    const float* __restrict__ W,     const float* __restrict__ bb_,
    const float* __restrict__ W_in,  const float* __restrict__ b_in,
    const float* __restrict__ W_upd, const float* __restrict__ b_upd,
    const float* __restrict__ W_rst, const float* __restrict__ b_rst,
    float* __restrict__ out)   // FP32 output: [new_hidden (B,H); ode_out (T,B,H)]
{
  __shared__ bf16 weffF[32][64][8];      // W_eff A-frags: [htg*4+kk][lane][8] (32KB)
  __shared__ bf16 zt[2][2][16][LDSW];    // [pair][buf][row][h] ping-pong (17KB)
  __shared__ float sbias[kH];
  __shared__ float stsv[kT];

  const int tid   = threadIdx.x;
  const int wv    = tid >> 6;          // 0..3
  const int pair  = wv >> 1;           // row group (16 rows)
  const int hHalf = wv & 1;            // h half (64 cols)
  const int lane  = tid & 63;
  const int qd    = lane >> 4;
  const int l16   = lane & 15;
  const int r0    = blockIdx.x * ROWS;
  const int grow  = r0 + pair*16 + l16;     // lane's global batch row
  const int hb    = hHalf*64 + 4*qd;        // lane's h col base; hc(ht)=hb+16*ht
  const int rowb  = hHalf*64 + l16;         // lane's W row base; row(ht)=rowb+16*ht

  if (tid < kT) stsv[tid] = ts[tid];
  if (tid < kH) sbias[tid] = bb_[tid];

  // ---- stage W_eff = W .* wiring into LDS A-frag order (8 frags/wave) ----
#pragma unroll
  for (int j = 0; j < 8; ++j) {
    int f = wv*8 + j, htg = f >> 2, kk = f & 3;
    const float* wp = W      + (size_t)(htg*16 + l16)*kH + kk*32 + qd*8;
    const float* mp = wiring + (size_t)(htg*16 + l16)*kH + kk*32 + qd*8;
    float4 w0 = *(const float4*)wp, w1 = *(const float4*)(wp+4);
    float4 m0 = *(const float4*)mp, m1 = *(const float4*)(mp+4);
    bf16x8 t;
    t[0]=(bf16)(w0.x*m0.x); t[1]=(bf16)(w0.y*m0.y);
    t[2]=(bf16)(w0.z*m0.z); t[3]=(bf16)(w0.w*m0.w);
    t[4]=(bf16)(w1.x*m1.x); t[5]=(bf16)(w1.y*m1.y);
    t[6]=(bf16)(w1.z*m1.z); t[7]=(bf16)(w1.w*m1.w);
    *(bf16x8*)&weffF[f][lane][0] = t;
  }

  // ---- gates: B-frags direct from global (no LDS staging), kk-outer ----
  const float* hrow = hidden + (size_t)grow*kH;
  const float* xrow = x      + (size_t)grow*kIn;

  f32x4 XP[NHT], Ug[NHT], Rg[NHT];
#pragma unroll
  for (int ht = 0; ht < NHT; ++ht) {
    int hc = hb + 16*ht;
    float4 bi = *(const float4*)(b_in  + hc);
    float4 bu = *(const float4*)(b_upd + hc);
    float4 br = *(const float4*)(b_rst + hc);
    XP[ht] = f32x4{bi.x, bi.y, bi.z, bi.w};
    Ug[ht] = f32x4{bu.x, bu.y, bu.z, bu.w};
    Rg[ht] = f32x4{br.x, br.y, br.z, br.w};
  }
#pragma unroll
  for (int kk = 0; kk < 4; ++kk) {           // hidden part: k = kk*32+qd*8
    bf16x8 cbk = cvt8(hrow + kk*32 + qd*8);
#pragma unroll
    for (int ht = 0; ht < NHT; ++ht) {
      size_t ro = (size_t)(rowb + 16*ht)*HIN + kk*32 + qd*8;
      Ug[ht] = __builtin_amdgcn_mfma_f32_16x16x32_bf16(cvt8(W_upd + ro), cbk, Ug[ht], 0,0,0);
      Rg[ht] = __builtin_amdgcn_mfma_f32_16x16x32_bf16(cvt8(W_rst + ro), cbk, Rg[ht], 0,0,0);
    }
  }
#pragma unroll
  for (int kk = 0; kk < 4; ++kk) {           // x part: k = 128 + kk*32+qd*8
    bf16x8 cbk = cvt8(xrow + kk*32 + qd*8);
#pragma unroll
    for (int ht = 0; ht < NHT; ++ht) {
      size_t ro = (size_t)(rowb + 16*ht)*HIN + kH + kk*32 + qd*8;
      size_t ri = (size_t)(rowb + 16*ht)*kIn + kk*32 + qd*8;
      Ug[ht] = __builtin_amdgcn_mfma_f32_16x16x32_bf16(cvt8(W_upd + ro), cbk, Ug[ht], 0,0,0);
      Rg[ht] = __builtin_amdgcn_mfma_f32_16x16x32_bf16(cvt8(W_rst + ro), cbk, Rg[ht], 0,0,0);
      XP[ht] = __builtin_amdgcn_mfma_f32_16x16x32_bf16(cvt8(W_in  + ri), cbk, XP[ht], 0,0,0);
    }
  }

  f32x4 h[NHT], z[NHT], hacc[NHT], xp1[NHT], K[NHT];
  bf16x4 ub[NHT];
#pragma unroll
  for (int ht = 0; ht < NHT; ++ht) {
    float4 hv = *(const float4*)(hrow + hb + 16*ht);
    h[ht][0] = sigmoid_(Rg[ht][0]) * hv.x;
    h[ht][1] = sigmoid_(Rg[ht][1]) * hv.y;
    h[ht][2] = sigmoid_(Rg[ht][2]) * hv.z;
    h[ht][3] = sigmoid_(Rg[ht][3]) * hv.w;
#pragma unroll
    for (int i = 0; i < 4; ++i) {
      ub[ht][i]  = (bf16)sigmoid_(Ug[ht][i]);   // u in 8 VGPRs
      xp1[ht][i] = XP[ht][i] + 1.0f;            // x_proj + 1 (folds tanh const)
      z[ht][i]   = h[ht][i];
    }
  }

  // ---- z0 = h0 into buf0; ode_out[0] = h0 ----
  float* odeB = out + (size_t)kB*kH;
#pragma unroll
  for (int ht = 0; ht < NHT; ++ht) {
    bf16x4 p;
    p[0]=(bf16)h[ht][0]; p[1]=(bf16)h[ht][1]; p[2]=(bf16)h[ht][2]; p[3]=(bf16)h[ht][3];
    *(bf16x4*)&zt[pair][0][l16][hb + 16*ht] = p;
    *(f32x4*)(odeB + (size_t)grow*kH + hb + 16*ht) = h[ht];
  }
  __syncthreads();   // weffF + z0 visible to pair peer

  // ---- RK4 loop: 1 barrier/stage; buffers statically ping-ponged ----
  auto feval = [&](const bf16 (*Y)[LDSW]) {
#pragma unroll
    for (int ht = 0; ht < NHT; ++ht)
      K[ht] = *(const f32x4*)&sbias[hb + 16*ht];
#pragma unroll
    for (int kk = 0; kk < 4; ++kk) {
      bf16x8 zfk = *(const bf16x8*)&Y[l16][kk*32 + qd*8];
#pragma unroll
      for (int ht = 0; ht < NHT; ++ht) {
        bf16x8 wf = *(const bf16x8*)&weffF[hHalf*16 + ht*4 + kk][lane][0];
        K[ht] = __builtin_amdgcn_mfma_f32_16x16x32_bf16(wf, zfk, K[ht], 0,0,0);
      }
    }
  };
  auto zwrite = [&](bf16 (*Y)[LDSW]) {
#pragma unroll
    for (int ht = 0; ht < NHT; ++ht) {
      bf16x4 p;
      p[0]=(bf16)z[ht][0]; p[1]=(bf16)z[ht][1]; p[2]=(bf16)z[ht][2]; p[3]=(bf16)z[ht][3];
      *(bf16x4*)&Y[l16][hb + 16*ht] = p;
    }
  };
  auto kvf = [&](int ht, int i) -> float {
    float m = 2.8853900817779268f * K[ht][i];      // 2*log2(e) * K
    float e = __builtin_amdgcn_exp2f(m);
    float r = __builtin_amdgcn_rcpf(1.0f + e);
    return __builtin_fmaf(-2.0f, r, xp1[ht][i] - z[ht][i]);  // tanh(K)+xp-z
  };

  bf16 (*zb0)[LDSW] = zt[pair][0];
  bf16 (*zb1)[LDSW] = zt[pair][1];

  for (int t = 1; t < kT; ++t) {
    float dt = stsv[t] - stsv[t-1];
    float c6 = dt * (1.0f/6.0f);
    float c3 = dt * (1.0f/3.0f);
    float ch = 0.5f * dt;

    // stage 1: read b0, write b1
    feval(zb0);
#pragma unroll
    for (int ht = 0; ht < NHT; ++ht)
#pragma unroll
      for (int i = 0; i < 4; ++i) {
        float kv = kvf(ht, i);
        hacc[ht][i] = __builtin_fmaf(c6, kv, h[ht][i]);
        z[ht][i]    = __builtin_fmaf(ch, kv, h[ht][i]);
      }
    zwrite(zb1);
    __syncthreads();

    // stage 2: read b1, write b0
    feval(zb1);
#pragma unroll
    for (int ht = 0; ht < NHT; ++ht)
#pragma unroll
      for (int i = 0; i < 4; ++i) {
        float kv = kvf(ht, i);
        hacc[ht][i] = __builtin_fmaf(c3, kv, hacc[ht][i]);
        z[ht][i]    = __builtin_fmaf(ch, kv, h[ht][i]);
      }
    zwrite(zb0);
    __syncthreads();

    // stage 3: read b0, write b1
    feval(zb0);
#pragma unroll
    for (int ht = 0; ht < NHT; ++ht)
#pragma unroll
      for (int i = 0; i < 4; ++i) {
        float kv = kvf(ht, i);
        hacc[ht][i] = __builtin_fmaf(c3, kv, hacc[ht][i]);
        z[ht][i]    = __builtin_fmaf(dt, kv, h[ht][i]);
      }
    zwrite(zb1);
    __syncthreads();

    // stage 4: read b1, write b0 (z = h_new)
    feval(zb1);
#pragma unroll
    for (int ht = 0; ht < NHT; ++ht)
#pragma unroll
      for (int i = 0; i < 4; ++i) {
        float kv = kvf(ht, i);
        h[ht][i] = __builtin_fmaf(c6, kv, hacc[ht][i]);
        z[ht][i] = h[ht][i];
      }
    zwrite(zb0);

    float* odet = odeB + (size_t)t*kB*kH + (size_t)grow*kH;
#pragma unroll
    for (int ht = 0; ht < NHT; ++ht)
      *(f32x4*)(odet + hb + 16*ht) = h[ht];     // ode_out[t]
    __syncthreads();
  }

  // ---- final blend: new_hidden = u*h_last + (1-u)*h0 (h0 from ode_out[0]) ----
#pragma unroll
  for (int ht = 0; ht < NHT; ++ht) {
    f32x4 h0v = *(const f32x4*)(odeB + (size_t)grow*kH + hb + 16*ht);
    float4 p;
    float uu;
    uu=(float)ub[ht][0]; p.x = uu*h[ht][0] + (1.0f-uu)*h0v[0];
    uu=(float)ub[ht][1]; p.y = uu*h[ht][1] + (1.0f-uu)*h0v[1];
    uu=(float)ub[ht][2]; p.z = uu*h[ht][2] + (1.0f-uu)*h0v[2];
    uu=(float)ub[ht][3]; p.w = uu*h[ht][3] + (1.0f-uu)*h0v[3];
    *(float4*)(out + (size_t)grow*kH + hb + 16*ht) = p;
  }
}

extern "C" void kernel_launch(void* const* d_in, const int* in_sizes, int n_in,
                              void* d_out, int out_size, void* d_ws, size_t ws_size,
                              hipStream_t stream) {
  (void)d_ws; (void)ws_size; (void)out_size;
  // Resolve input order from in_sizes (insurance; documented order expected).
  int ix=0, ih=1, its=2, iwr=3, iW=4, ib=5, iWin=6, ibin=7, iWu=8, ibu=9, iWr=10, ibr=11;
  if (n_in == 12 && in_sizes[2] != 10 && in_sizes[5] == 10) {
    // case-insensitive name-sorted: b,b_in,b_rst,b_upd,hidden,time_span,W,W_in,W_rst,W_upd,wiring,x
    ib=0; ibin=1; ibr=2; ibu=3; ih=4; its=5; iW=6; iWin=7; iWr=8; iWu=9; iwr=10; ix=11;
  }
  const float* x      = (const float*)d_in[ix];
  const float* hidden = (const float*)d_in[ih];
  const float* ts     = (const float*)d_in[its];
  const float* wiring = (const float*)d_in[iwr];
  const float* W      = (const float*)d_in[iW];
  const float* b      = (const float*)d_in[ib];
  const float* W_in   = (const float*)d_in[iWin];
  const float* b_in   = (const float*)d_in[ibin];
  const float* W_upd  = (const float*)d_in[iWu];
  const float* b_upd  = (const float*)d_in[ibu];
  const float* W_rst  = (const float*)d_in[iWr];
  const float* b_rst  = (const float*)d_in[ibr];

  dim3 grid(kB / ROWS);   // 1024 blocks (32 rows each)
  dim3 block(256);
  ltc_kernel<<<grid, block, 0, stream>>>(x, hidden, ts, wiring, W, b,
                                         W_in, b_in, W_upd, b_upd, W_rst, b_rst,
                                         (float*)d_out);
}